// Round 9
// baseline (634.846 us; speedup 1.0000x reference)
//
#include <hip/hip_runtime.h>

// n=64 grid; output A is (3*n^2) x (3*n^2) = 12288 x 12288 float32, mostly zeros.
// Round 4: rocclr fillBufferAligned (hipMemsetAsync) = 400us with 4x write
// amplification (2.36 GB for 604 MB). Custom nontemporal float4 zero-fill.
// Round 5 fix: __builtin_nontemporal_store needs a clang native vector type,
// not HIP_vector_type float4 -> use ext_vector_type(4) float.

constexpr int   nG    = 64;
constexpr int   NN    = nG * nG;     // 4096
constexpr int   BIG   = 3 * NN;      // 12288
constexpr float LR    = 0.001f;
constexpr float SQRT2 = 1.41421356237309504880f;

typedef float v4f __attribute__((ext_vector_type(4)));

__global__ void zero_kernel(v4f* __restrict__ p, size_t n4) {
    size_t i      = (size_t)blockIdx.x * blockDim.x + threadIdx.x;
    size_t stride = (size_t)gridDim.x * blockDim.x;
    v4f z = (v4f)(0.0f);
    for (; i < n4; i += stride)
        __builtin_nontemporal_store(z, &p[i]);
}

__global__ void maxc_kernel(const float* __restrict__ c, float* __restrict__ out) {
    int t = threadIdx.x;
    float m = -1e30f;
    for (int i = t; i < NN; i += 256) m = fmaxf(m, c[i]);
#pragma unroll
    for (int off = 32; off >= 1; off >>= 1) m = fmaxf(m, __shfl_down(m, off, 64));
    __shared__ float s[4];
    if ((t & 63) == 0) s[t >> 6] = m;
    __syncthreads();
    if (t == 0) out[0] = fmaxf(fmaxf(s[0], s[1]), fmaxf(s[2], s[3]));
}

// Flat index g = i*n + ii (block i = column of the n x n fields, ii = row within block).
// cflat[g] = c[ii, i]  -> row-major flat f = ii*n + i.
// kx = k_x - LR*dk, ky = k_y - LR*dk, same transposed-flat mapping.
// dx = dy = (DT/CN)*max(c)*sqrt(2) = 10*max(c)*sqrt(2).
__global__ void scatter_kernel(const float* __restrict__ c, const float* __restrict__ kp,
                               const float* __restrict__ kx, const float* __restrict__ ky,
                               const float* __restrict__ dk, const float* __restrict__ maxc,
                               float* __restrict__ A) {
    int g = blockIdx.x * blockDim.x + threadIdx.x;
    if (g >= NN) return;
    int ii = g & (nG - 1);
    int i  = g >> 6;
    int f  = ii * nG + i;

    float d   = 10.0f * maxc[0] * SQRT2;
    float id  = 1.0f / d;
    float id2 = id * id;

    float cv   = c[f];
    float kpv  = kp[ii];
    float minv = 1.0f / (1.0f - 0.5f * kpv);
    float mp   = 1.0f + 0.5f * kpv;

    float kxc   = kx[f] - LR * dk[f];
    float nxinv = 1.0f / (1.0f + 0.5f * kxc);
    float nxp   = 1.0f - 0.5f * kxc;

    float kyc   = ky[f] - LR * dk[f];
    float nyinv = 1.0f / (1.0f + 0.5f * kyc);
    float nyp   = 1.0f - 0.5f * kyc;

    bool hasE = (i  < nG - 1);   // neighbor g+n exists (next block)
    bool hasW = (i  > 0);        // neighbor g-n exists
    bool hasU = (ii < nG - 1);   // g+1 within block
    bool hasS = (ii > 0);        // g-1 within block

    float cpn = 0.f, cmn = 0.f, cp1 = 0.f;
    float nxinvE = 0.f, nxpE = 0.f, nyinvU = 0.f, nypU = 0.f;
    if (hasE) {
        cpn = c[f + 1];                              // cflat[g+n] = c[ii, i+1]
        float kxE = kx[f + 1] - LR * dk[f + 1];
        nxinvE = 1.0f / (1.0f + 0.5f * kxE);
        nxpE   = 1.0f - 0.5f * kxE;
    }
    if (hasW) cmn = c[f - 1];                        // cflat[g-n] = c[ii, i-1]
    if (hasU) {
        cp1 = c[f + nG];                             // cflat[g+1] = c[ii+1, i]
        float kyU = ky[f + nG] - LR * dk[f + nG];
        nyinvU = 1.0f / (1.0f + 0.5f * kyU);
        nypU   = 1.0f - 0.5f * kyU;
    }

    size_t r0 = (size_t)g * BIG;                 // A1x rows
    size_t r1 = (size_t)(NN + g) * BIG;          // A2x rows
    size_t r2 = (size_t)(2 * NN + g) * BIG;      // A3x rows

    float cv2 = cv * cv;

    // ---- A11 (pentadiagonal: -n, -1, 0, +1, +n) ----
    float diag = minv * mp
               + minv * ( -cv2 * id2 * (nxinv + (hasE ? nxinvE : 0.f))
                          -cv2 * id2 * nyinv
                          -(hasU ? cp1 * cp1 * id2 * nyinvU : 0.f) );
    if (hasW) A[r0 + (g - nG)] = minv * cv * cmn * id2 * nxinv;
    if (hasS) A[r0 + (g - 1)]  = minv * cv2 * id2 * nyinv;
    A[r0 + g] = diag;
    if (hasU) A[r0 + (g + 1)]  = minv * cp1 * cp1 * id2 * nyinvU;
    if (hasE) A[r0 + (g + nG)] = minv * cv * cpn * id2 * nxinvE;

    // ---- A12 (diag, +n) ----
    A[r0 + NN + g] = minv * cv * id * nxinv * nxp;
    if (hasE) A[r0 + NN + g + nG] = -minv * cv * id * nxinvE * nxpE;

    // ---- A13 (diag, +1) ----
    A[r0 + 2 * NN + g] = minv * cv * id * nyinv * nyp;
    if (hasU) A[r0 + 2 * NN + g + 1] = -minv * cp1 * id * nyinvU * nypU;

    // ---- A21 (diag, -n) ----
    if (hasW) A[r1 + (g - nG)] = nxinv * cmn * id;
    A[r1 + g] = -nxinv * cv * id;

    // ---- A22 (diag) ----
    A[r1 + NN + g] = nxinv * nxp;

    // ---- A31 (diag, -1) ----
    if (hasS) A[r2 + (g - 1)] = nyinv * cv * id;
    A[r2 + g] = -nyinv * cv * id;

    // ---- A33 (diag) ----
    A[r2 + 2 * NN + g] = nyinv * nyp;
}

extern "C" void kernel_launch(void* const* d_in, const int* in_sizes, int n_in,
                              void* d_out, int out_size, void* d_ws, size_t ws_size,
                              hipStream_t stream) {
    const float* c  = (const float*)d_in[0];
    const float* kp = (const float*)d_in[1];
    const float* kx = (const float*)d_in[2];
    const float* ky = (const float*)d_in[3];
    const float* dk = (const float*)d_in[4];
    float* A = (float*)d_out;
    float* ws = (float*)d_ws;

    // Custom vectorized zero-fill (out_size = 12288^2, divisible by 4).
    size_t n4 = (size_t)out_size / 4;
    zero_kernel<<<2048, 256, 0, stream>>>((v4f*)A, n4);
    // max(c) over 4096 elements, single block.
    maxc_kernel<<<1, 256, 0, stream>>>(c, ws);
    // Write the nonzero entries (one thread per flat index g, <=15 stores each).
    scatter_kernel<<<NN / 256, 256, 0, stream>>>(c, kp, kx, ky, dk, ws, A);
}

// Round 10
// 593.076 us; speedup vs baseline: 1.0704x; 1.0704x over previous
//
#include <hip/hip_runtime.h>

// n=64 grid; output A is (3*n^2) x (3*n^2) = 12288 x 12288 float32, mostly zeros.
// Round 9 post-mortem: the ~400us/2.4GB fillBufferAligned dispatches are the
// HARNESS's per-iteration 0xAA re-poison of d_out+d_ws (at 6 TB/s = write
// ceiling, no amplification) and are included in dur_us (~480us fixed cost).
// The kernel-controllable part is: fill 604 MB + tiny maxc/scatter ~= 105us,
// vs 96us write roofline. rocclr's memset fill beat my nt zero_kernel by
// ~50us, so use hipMemsetAsync (round-4 structure, measured dur_us=594).

constexpr int   nG    = 64;
constexpr int   NN    = nG * nG;     // 4096
constexpr int   BIG   = 3 * NN;      // 12288
constexpr float LR    = 0.001f;
constexpr float SQRT2 = 1.41421356237309504880f;

__global__ void maxc_kernel(const float* __restrict__ c, float* __restrict__ out) {
    int t = threadIdx.x;
    float m = -1e30f;
    for (int i = t; i < NN; i += 256) m = fmaxf(m, c[i]);
#pragma unroll
    for (int off = 32; off >= 1; off >>= 1) m = fmaxf(m, __shfl_down(m, off, 64));
    __shared__ float s[4];
    if ((t & 63) == 0) s[t >> 6] = m;
    __syncthreads();
    if (t == 0) out[0] = fmaxf(fmaxf(s[0], s[1]), fmaxf(s[2], s[3]));
}

// Flat index g = i*n + ii (block i = column of the n x n fields, ii = row within block).
// cflat[g] = c[ii, i]  -> row-major flat f = ii*n + i.
// kx = k_x - LR*dk, ky = k_y - LR*dk, same transposed-flat mapping.
// dx = dy = (DT/CN)*max(c)*sqrt(2) = 10*max(c)*sqrt(2).
__global__ void scatter_kernel(const float* __restrict__ c, const float* __restrict__ kp,
                               const float* __restrict__ kx, const float* __restrict__ ky,
                               const float* __restrict__ dk, const float* __restrict__ maxc,
                               float* __restrict__ A) {
    int g = blockIdx.x * blockDim.x + threadIdx.x;
    if (g >= NN) return;
    int ii = g & (nG - 1);
    int i  = g >> 6;
    int f  = ii * nG + i;

    float d   = 10.0f * maxc[0] * SQRT2;
    float id  = 1.0f / d;
    float id2 = id * id;

    float cv   = c[f];
    float kpv  = kp[ii];
    float minv = 1.0f / (1.0f - 0.5f * kpv);
    float mp   = 1.0f + 0.5f * kpv;

    float kxc   = kx[f] - LR * dk[f];
    float nxinv = 1.0f / (1.0f + 0.5f * kxc);
    float nxp   = 1.0f - 0.5f * kxc;

    float kyc   = ky[f] - LR * dk[f];
    float nyinv = 1.0f / (1.0f + 0.5f * kyc);
    float nyp   = 1.0f - 0.5f * kyc;

    bool hasE = (i  < nG - 1);   // neighbor g+n exists (next block)
    bool hasW = (i  > 0);        // neighbor g-n exists
    bool hasU = (ii < nG - 1);   // g+1 within block
    bool hasS = (ii > 0);        // g-1 within block

    float cpn = 0.f, cmn = 0.f, cp1 = 0.f;
    float nxinvE = 0.f, nxpE = 0.f, nyinvU = 0.f, nypU = 0.f;
    if (hasE) {
        cpn = c[f + 1];                              // cflat[g+n] = c[ii, i+1]
        float kxE = kx[f + 1] - LR * dk[f + 1];
        nxinvE = 1.0f / (1.0f + 0.5f * kxE);
        nxpE   = 1.0f - 0.5f * kxE;
    }
    if (hasW) cmn = c[f - 1];                        // cflat[g-n] = c[ii, i-1]
    if (hasU) {
        cp1 = c[f + nG];                             // cflat[g+1] = c[ii+1, i]
        float kyU = ky[f + nG] - LR * dk[f + nG];
        nyinvU = 1.0f / (1.0f + 0.5f * kyU);
        nypU   = 1.0f - 0.5f * kyU;
    }

    size_t r0 = (size_t)g * BIG;                 // A1x rows
    size_t r1 = (size_t)(NN + g) * BIG;          // A2x rows
    size_t r2 = (size_t)(2 * NN + g) * BIG;      // A3x rows

    float cv2 = cv * cv;

    // ---- A11 (pentadiagonal: -n, -1, 0, +1, +n) ----
    float diag = minv * mp
               + minv * ( -cv2 * id2 * (nxinv + (hasE ? nxinvE : 0.f))
                          -cv2 * id2 * nyinv
                          -(hasU ? cp1 * cp1 * id2 * nyinvU : 0.f) );
    if (hasW) A[r0 + (g - nG)] = minv * cv * cmn * id2 * nxinv;
    if (hasS) A[r0 + (g - 1)]  = minv * cv2 * id2 * nyinv;
    A[r0 + g] = diag;
    if (hasU) A[r0 + (g + 1)]  = minv * cp1 * cp1 * id2 * nyinvU;
    if (hasE) A[r0 + (g + nG)] = minv * cv * cpn * id2 * nxinvE;

    // ---- A12 (diag, +n) ----
    A[r0 + NN + g] = minv * cv * id * nxinv * nxp;
    if (hasE) A[r0 + NN + g + nG] = -minv * cv * id * nxinvE * nxpE;

    // ---- A13 (diag, +1) ----
    A[r0 + 2 * NN + g] = minv * cv * id * nyinv * nyp;
    if (hasU) A[r0 + 2 * NN + g + 1] = -minv * cp1 * id * nyinvU * nypU;

    // ---- A21 (diag, -n) ----
    if (hasW) A[r1 + (g - nG)] = nxinv * cmn * id;
    A[r1 + g] = -nxinv * cv * id;

    // ---- A22 (diag) ----
    A[r1 + NN + g] = nxinv * nxp;

    // ---- A31 (diag, -1) ----
    if (hasS) A[r2 + (g - 1)] = nyinv * cv * id;
    A[r2 + g] = -nyinv * cv * id;

    // ---- A33 (diag) ----
    A[r2 + 2 * NN + g] = nyinv * nyp;
}

extern "C" void kernel_launch(void* const* d_in, const int* in_sizes, int n_in,
                              void* d_out, int out_size, void* d_ws, size_t ws_size,
                              hipStream_t stream) {
    const float* c  = (const float*)d_in[0];
    const float* kp = (const float*)d_in[1];
    const float* kx = (const float*)d_in[2];
    const float* ky = (const float*)d_in[3];
    const float* dk = (const float*)d_in[4];
    float* A = (float*)d_out;
    float* ws = (float*)d_ws;

    // Zero-fill the 604 MB output with rocclr's tuned fill (runs at ~6 TB/s,
    // the achievable write ceiling; beat our custom nt-store kernel by ~50us).
    hipMemsetAsync(d_out, 0, (size_t)out_size * sizeof(float), stream);
    // max(c) over 4096 elements, single block.
    maxc_kernel<<<1, 256, 0, stream>>>(c, ws);
    // Write the nonzero entries (one thread per flat index g, <=15 stores each).
    scatter_kernel<<<NN / 256, 256, 0, stream>>>(c, kp, kx, ky, dk, ws, A);
}